// Round 5
// baseline (735.253 us; speedup 1.0000x reference)
//
#include <hip/hip_runtime.h>
#include <hip/hip_bf16.h>
#include <math.h>

#define DIM   384
#define HEADS 8
#define HD    48
#define NTOK  32768   // 8 * 64 * 64
#define NWIN  512     // 8 images * 64 windows

typedef __attribute__((ext_vector_type(8))) short bf16x8;
typedef __attribute__((ext_vector_type(8))) unsigned short u16x8;
typedef __attribute__((ext_vector_type(4))) float f32x4;

__device__ __forceinline__ float bf2f(unsigned short u) {
    unsigned int v = ((unsigned int)u) << 16;
    return __uint_as_float(v);
}
__device__ __forceinline__ unsigned short f2bf(float f) {
    unsigned int x = __float_as_uint(f);
    unsigned int r = (x + 0x7fffu + ((x >> 16) & 1u)) >> 16;  // RNE
    return (unsigned short)r;
}

// token (window order) -> source pixel of x (accounting for roll by -SHIFT)
__device__ __forceinline__ void tok2src(int tok, int& b, int& hs, int& ws) {
    int bb  = tok >> 12;
    int win = (tok >> 6) & 63;
    int t   = tok & 63;
    int hi = win >> 3, wi = win & 7;
    int r  = t >> 3,  cc = t & 7;
    b  = bb;
    hs = (hi * 8 + r  + 4) & 63;
    ws = (wi * 8 + cc + 4) & 63;
}

// ------------- merged weight convert: 4 segments f32 [K][N] -> bf16 [N][K] --
__global__ __launch_bounds__(256) void k_wt4(const float* __restrict__ qkv_w,
                                             const float* __restrict__ proj_w,
                                             const float* __restrict__ w1,
                                             const float* __restrict__ w2,
                                             unsigned short* __restrict__ d0,
                                             unsigned short* __restrict__ d1,
                                             unsigned short* __restrict__ d2,
                                             unsigned short* __restrict__ d3) {
    int idx = blockIdx.x * 256 + threadIdx.x;
    const float* W; unsigned short* Wt; int K, N, loc;
    if (idx < 442368)       { W = qkv_w;  Wt = d0; K = 384;  N = 1152; loc = idx; }
    else if (idx < 589824)  { W = proj_w; Wt = d1; K = 384;  N = 384;  loc = idx - 442368; }
    else if (idx < 1179648) { W = w1;     Wt = d2; K = 384;  N = 1536; loc = idx - 589824; }
    else                    { W = w2;     Wt = d3; K = 1536; N = 384;  loc = idx - 1179648; }
    int n = loc / K, k = loc - n * K;
    Wt[loc] = f2bf(W[(size_t)k * N + n]);
}

// -------- gather + LayerNorm1, per (b, image-row hs), coalesced ------------
__global__ __launch_bounds__(256) void k_ln1(const float* __restrict__ x,
                                             const float* __restrict__ g,
                                             const float* __restrict__ bt,
                                             unsigned short* __restrict__ ln1) {
    int blk = blockIdx.x;           // b*64 + hs
    int b  = blk >> 6, hs = blk & 63;
    int t  = threadIdx.x;
    int w  = t & 63, cg = t >> 6;   // pixel, channel-group (4)
    const float* row = x + (size_t)b * DIM * 4096 + hs * 64;

    float sum = 0.f, sq = 0.f;
    for (int i = 0; i < 96; i++) {
        int c = i * 4 + cg;
        float v = row[(size_t)c * 4096 + w];
        sum += v; sq += v * v;
    }
    __shared__ float red[2][4][64];
    __shared__ float mean_s[64], rstd_s[64];
    red[0][cg][w] = sum; red[1][cg][w] = sq;
    __syncthreads();
    if (t < 64) {
        float s  = red[0][0][t] + red[0][1][t] + red[0][2][t] + red[0][3][t];
        float q2 = red[1][0][t] + red[1][1][t] + red[1][2][t] + red[1][3][t];
        float mean = s * (1.0f / DIM);
        float var  = q2 * (1.0f / DIM) - mean * mean;
        mean_s[t] = mean;
        rstd_s[t] = rsqrtf(var + 1e-5f);
    }
    __syncthreads();

    int wp = t >> 2, seg = t & 3;
    int hr = (hs + 60) & 63, wr = (wp + 60) & 63;
    int tok = ((b * 8 + (hr >> 3)) * 8 + (wr >> 3)) * 64 + (hr & 7) * 8 + (wr & 7);

    __shared__ __align__(16) unsigned short tile[64][72];
    for (int chunk = 0; chunk < 6; chunk++) {
        float mean = mean_s[w], rstd = rstd_s[w];
        #pragma unroll
        for (int it = 0; it < 16; it++) {
            int cl = it * 4 + cg;
            int c  = chunk * 64 + cl;
            float v = row[(size_t)c * 4096 + w];
            tile[w][cl] = f2bf((v - mean) * rstd * g[c] + bt[c]);
        }
        __syncthreads();
        u16x8 v0 = *(const u16x8*)&tile[wp][seg * 16];
        u16x8 v1 = *(const u16x8*)&tile[wp][seg * 16 + 8];
        unsigned short* op = ln1 + (size_t)tok * DIM + chunk * 64 + seg * 16;
        *(u16x8*)op = v0;
        *(u16x8*)(op + 8) = v1;
        __syncthreads();
    }
}

// ---------------- MFMA GEMM: C[M,N] = A[M,K](bf16) * Bt[N,K]^T(bf16) + bias
// 128x128 tile, 4 waves, 4x4 16x16x32 MFMA, BK=32.
// Round-2 proven single-buffer 2-barrier K-loop (80 VGPR, high occupancy) +
// XCD-aware block remap (FETCH 103->17MB) + LDS-staged bf16 epilogue
// (WRITE 200->98MB). Double-buffering deliberately NOT used: it blew VGPR
// to 160 and collapsed occupancy 31%->11% (round 4).
// EPI: 0 bias->bf16; 1 bias+gelu->bf16; 2 bias+residual gather->f32; 3 bias->f32
template <int EPI>
__global__ __launch_bounds__(256) void k_gemm_mfma(
        const unsigned short* __restrict__ A,
        const unsigned short* __restrict__ Bt,
        const float* __restrict__ bias,
        void* __restrict__ Cout,
        const float* __restrict__ xres,
        int N, int K, int GX) {
    // 17408 B shared: staging uses [0,8192) A + [8192,16384) B ushorts;
    // epilogue reuses [0,8704) ushorts as [64][136] scratch.
    __shared__ __align__(16) unsigned short smem[8704];
    unsigned short* Alds = smem;
    unsigned short* Blds = smem + 4096;
    int tid  = threadIdx.x;
    int lane = tid & 63;
    int wave = tid >> 6;
    int wm = wave >> 1, wn = wave & 1;
    int quad = lane >> 4, l15 = lane & 15;

    // XCD swizzle: all GX n-blocks of one m-row-block land on one XCD
    int l   = blockIdx.x;
    int xcd = l & 7;
    int r_  = l >> 3;
    int bx  = r_ % GX;
    int by  = (r_ / GX) * 8 + xcd;
    int m0 = by * 128, n0 = bx * 128;

    f32x4 acc[4][4] = {};

    for (int k0 = 0; k0 < K; k0 += 32) {
        #pragma unroll
        for (int i = 0; i < 2; i++) {
            int c = wave + i * 4;       // 0..7
            int g = c & 3, j = c >> 2;  // kgroup, row-half
            const unsigned short* gpA = A + (size_t)(m0 + j * 64 + lane) * K + k0 + g * 8;
            __builtin_amdgcn_global_load_lds(
                (const __attribute__((address_space(1))) void*)gpA,
                (__attribute__((address_space(3))) void*)&Alds[(g * 128 + j * 64) * 8],
                16, 0, 0);
            const unsigned short* gpB = Bt + (size_t)(n0 + j * 64 + lane) * K + k0 + g * 8;
            __builtin_amdgcn_global_load_lds(
                (const __attribute__((address_space(1))) void*)gpB,
                (__attribute__((address_space(3))) void*)&Blds[(g * 128 + j * 64) * 8],
                16, 0, 0);
        }
        __syncthreads();

        bf16x8 af[4], bfr[4];
        #pragma unroll
        for (int r = 0; r < 4; r++)
            af[r] = *(const bf16x8*)&Alds[(quad * 128 + wm * 64 + r * 16 + l15) * 8];
        #pragma unroll
        for (int r2 = 0; r2 < 4; r2++)
            bfr[r2] = *(const bf16x8*)&Blds[(quad * 128 + wn * 64 + r2 * 16 + l15) * 8];
        #pragma unroll
        for (int r = 0; r < 4; r++)
            #pragma unroll
            for (int r2 = 0; r2 < 4; r2++)
                acc[r][r2] = __builtin_amdgcn_mfma_f32_16x16x32_bf16(
                                 af[r], bfr[r2], acc[r][r2], 0, 0, 0);
        __syncthreads();
    }

    float bn[4];
    #pragma unroll
    for (int r2 = 0; r2 < 4; r2++) bn[r2] = bias[n0 + wn * 64 + r2 * 16 + l15];

    if (EPI == 0 || EPI == 1) {
        unsigned short* st = smem;    // [64][136] ushort
        for (int p = 0; p < 2; p++) {
            __syncthreads();
            if (wm == p) {
                #pragma unroll
                for (int r = 0; r < 4; r++)
                    #pragma unroll
                    for (int reg = 0; reg < 4; reg++) {
                        int rowl = r * 16 + quad * 4 + reg;
                        #pragma unroll
                        for (int r2 = 0; r2 < 4; r2++) {
                            float v = acc[r][r2][reg] + bn[r2];
                            if (EPI == 1)
                                v = 0.5f * v * (1.0f + erff(v * 0.70710678118654752f));
                            st[rowl * 136 + wn * 64 + r2 * 16 + l15] = f2bf(v);
                        }
                    }
            }
            __syncthreads();
            #pragma unroll
            for (int s = 0; s < 4; s++) {
                int idx  = s * 256 + tid;
                int rowl = idx >> 4;
                int ch   = idx & 15;
                u16x8 v = *(const u16x8*)&st[rowl * 136 + ch * 8];
                *(u16x8*)((unsigned short*)Cout +
                          (size_t)(m0 + p * 64 + rowl) * N + n0 + ch * 8) = v;
            }
        }
    } else {
        #pragma unroll
        for (int r2 = 0; r2 < 4; r2++) {
            int n = n0 + wn * 64 + r2 * 16 + l15;
            #pragma unroll
            for (int r = 0; r < 4; r++) {
                #pragma unroll
                for (int reg = 0; reg < 4; reg++) {
                    int m = m0 + wm * 64 + r * 16 + quad * 4 + reg;
                    float v = acc[r][r2][reg] + bn[r2];
                    if (EPI == 2) {
                        int b, hs, ws_;
                        tok2src(m, b, hs, ws_);
                        v += xres[(((size_t)b * DIM + n) * 64 + hs) * 64 + ws_];
                    }
                    ((float*)Cout)[(size_t)m * N + n] = v;
                }
            }
        }
    }
}

// ---------------- attention per (window, head) — round-2 proven version -----
__global__ __launch_bounds__(64) void k_attn(const unsigned short* __restrict__ qkv,
                                             unsigned short* __restrict__ attn) {
    int win  = blockIdx.x >> 3;
    int head = blockIdx.x & 7;
    int t    = threadIdx.x;
    int tok0 = win * 64;

    __shared__ float Ks[64][52];
    __shared__ float Vs[64][52];

    const unsigned short* rowp = qkv + (size_t)(tok0 + t) * (3 * DIM);
    #pragma unroll
    for (int d = 0; d < HD; d++) {
        Ks[t][d] = bf2f(rowp[DIM + head * HD + d]);
        Vs[t][d] = bf2f(rowp[2 * DIM + head * HD + d]);
    }
    const float scale = 0.14433756729740643f;  // 48^-0.5
    float q[HD];
    #pragma unroll
    for (int d = 0; d < HD; d++) q[d] = bf2f(rowp[head * HD + d]) * scale;
    __syncthreads();

    float s[64];
    float mx = -1e30f;
    #pragma unroll
    for (int m = 0; m < 64; m++) {
        float acc = 0.f;
        #pragma unroll
        for (int d4 = 0; d4 < HD / 4; d4++) {
            float4 kk = *(const float4*)&Ks[m][d4 * 4];
            acc += q[d4 * 4 + 0] * kk.x + q[d4 * 4 + 1] * kk.y
                 + q[d4 * 4 + 2] * kk.z + q[d4 * 4 + 3] * kk.w;
        }
        s[m] = acc;
        mx = fmaxf(mx, acc);
    }
    float denom = 0.f;
    #pragma unroll
    for (int m = 0; m < 64; m++) {
        float e = __expf(s[m] - mx);
        s[m] = e;
        denom += e;
    }
    float inv = 1.0f / denom;
    float out[HD];
    #pragma unroll
    for (int d = 0; d < HD; d++) out[d] = 0.f;
    #pragma unroll
    for (int m = 0; m < 64; m++) {
        float p = s[m] * inv;
        #pragma unroll
        for (int d4 = 0; d4 < HD / 4; d4++) {
            float4 vv = *(const float4*)&Vs[m][d4 * 4];
            out[d4 * 4 + 0] += p * vv.x;
            out[d4 * 4 + 1] += p * vv.y;
            out[d4 * 4 + 2] += p * vv.z;
            out[d4 * 4 + 3] += p * vv.w;
        }
    }
    unsigned short* op = attn + (size_t)(tok0 + t) * DIM + head * HD;
    #pragma unroll
    for (int d = 0; d < HD; d++) op[d] = f2bf(out[d]);
}

// ---------------- LayerNorm2 over y (f32) -> ln2 (bf16) ----------
__global__ __launch_bounds__(64) void k_ln2(const float* __restrict__ y,
                                            const float* __restrict__ g,
                                            const float* __restrict__ bt,
                                            unsigned short* __restrict__ out) {
    int tok = blockIdx.x;
    int t   = threadIdx.x;
    const float* row = y + (size_t)tok * DIM;
    float v[6];
    float sum = 0.f, sq = 0.f;
    #pragma unroll
    for (int i = 0; i < 6; i++) {
        v[i] = row[i * 64 + t];
        sum += v[i]; sq += v[i] * v[i];
    }
    #pragma unroll
    for (int o = 32; o > 0; o >>= 1) {
        sum += __shfl_xor(sum, o, 64);
        sq  += __shfl_xor(sq, o, 64);
    }
    float mean = sum * (1.0f / DIM);
    float var  = sq * (1.0f / DIM) - mean * mean;
    float rstd = rsqrtf(var + 1e-5f);
    unsigned short* orow = out + (size_t)tok * DIM;
    #pragma unroll
    for (int i = 0; i < 6; i++) {
        int c = i * 64 + t;
        orow[c] = f2bf((v[i] - mean) * rstd * g[c] + bt[c]);
    }
}

// ---------------- un-permute + transpose to [B,C,H,W] ------------
__global__ __launch_bounds__(256) void k_out(const float* __restrict__ hbuf,
                                             float* __restrict__ out) {
    int bh = blockIdx.x;
    int b = bh >> 6, h = bh & 63;
    int t = threadIdx.x;
    __shared__ float T[64][193];
    int hh = (h + 60) & 63;
    int hi = hh >> 3, r = hh & 7;
    for (int half = 0; half < 2; half++) {
        int c0 = half * 192;
        for (int idx = t; idx < 64 * 192; idx += 256) {
            int w = idx / 192;
            int c = idx - w * 192;
            int ww = (w + 60) & 63;
            int wi = ww >> 3, cc2 = ww & 7;
            int tok = ((b * 8 + hi) * 8 + wi) * 64 + r * 8 + cc2;
            T[w][c] = hbuf[(size_t)tok * DIM + c0 + c];
        }
        __syncthreads();
        for (int idx = t; idx < 64 * 192; idx += 256) {
            int cc = idx >> 6;
            int w  = idx & 63;
            out[(((size_t)b * DIM + c0 + cc) * 64 + h) * 64 + w] = T[w][cc];
        }
        __syncthreads();
    }
}

extern "C" void kernel_launch(void* const* d_in, const int* in_sizes, int n_in,
                              void* d_out, int out_size, void* d_ws, size_t ws_size,
                              hipStream_t stream) {
    const float* x      = (const float*)d_in[0];
    const float* qkv_w  = (const float*)d_in[1];
    const float* qkv_b  = (const float*)d_in[2];
    const float* proj_w = (const float*)d_in[3];
    const float* proj_b = (const float*)d_in[4];
    const float* ln1_g  = (const float*)d_in[5];
    const float* ln1_b  = (const float*)d_in[6];
    const float* ln2_g  = (const float*)d_in[7];
    const float* ln2_b  = (const float*)d_in[8];
    const float* w1     = (const float*)d_in[9];
    const float* b1     = (const float*)d_in[10];
    const float* w2     = (const float*)d_in[11];
    const float* b2     = (const float*)d_in[12];

    char* ws = (char*)d_ws;
    unsigned short* qkv_wt  = (unsigned short*)(ws + 0);
    unsigned short* proj_wt = (unsigned short*)(ws + 884736);
    unsigned short* w1t     = (unsigned short*)(ws + 1179648);
    unsigned short* w2t     = (unsigned short*)(ws + 2359296);
    unsigned short* ln1     = (unsigned short*)(ws + 4194304);
    unsigned short* qkv     = (unsigned short*)(ws + 29360128);
    unsigned short* attn    = (unsigned short*)(ws + 104857600);
    float*          y       = (float*)(ws + 130023424);
    unsigned short* ln2     = ln1;
    unsigned short* mid     = qkv;      // [32768][1536] bf16
    float*          hbuf    = y;

    k_wt4<<<6912, 256, 0, stream>>>(qkv_w, proj_w, w1, w2, qkv_wt, proj_wt, w1t, w2t);
    k_ln1<<<512, 256, 0, stream>>>(x, ln1_g, ln1_b, ln1);
    k_gemm_mfma<0><<<9 * 256, 256, 0, stream>>>(ln1, qkv_wt, qkv_b, qkv, nullptr, 1152, 384, 9);
    k_attn<<<NWIN * HEADS, 64, 0, stream>>>(qkv, attn);
    k_gemm_mfma<2><<<3 * 256, 256, 0, stream>>>(attn, proj_wt, proj_b, y, x, 384, 384, 3);
    k_ln2<<<NTOK, 64, 0, stream>>>(y, ln2_g, ln2_b, ln2);
    k_gemm_mfma<1><<<12 * 256, 256, 0, stream>>>(ln2, w1t, b1, mid, nullptr, 1536, 384, 12);
    k_gemm_mfma<3><<<3 * 256, 256, 0, stream>>>(mid, w2t, b2, hbuf, nullptr, 384, 1536, 3);
    k_out<<<NWIN, 256, 0, stream>>>(hbuf, (float*)d_out);
}

// Round 6
// 639.897 us; speedup vs baseline: 1.1490x; 1.1490x over previous
//
#include <hip/hip_runtime.h>
#include <hip/hip_bf16.h>
#include <math.h>

#define DIM   384
#define HEADS 8
#define HD    48
#define NTOK  32768   // 8 * 64 * 64
#define NWIN  512     // 8 images * 64 windows

typedef __attribute__((ext_vector_type(8))) short bf16x8;
typedef __attribute__((ext_vector_type(8))) unsigned short u16x8;
typedef __attribute__((ext_vector_type(4))) float f32x4;

__device__ __forceinline__ float bf2f(unsigned short u) {
    unsigned int v = ((unsigned int)u) << 16;
    return __uint_as_float(v);
}
__device__ __forceinline__ unsigned short f2bf(float f) {
    unsigned int x = __float_as_uint(f);
    unsigned int r = (x + 0x7fffu + ((x >> 16) & 1u)) >> 16;  // RNE
    return (unsigned short)r;
}

// token (window order) -> source pixel of x (accounting for roll by -SHIFT)
__device__ __forceinline__ void tok2src(int tok, int& b, int& hs, int& ws) {
    int bb  = tok >> 12;
    int win = (tok >> 6) & 63;
    int t   = tok & 63;
    int hi = win >> 3, wi = win & 7;
    int r  = t >> 3,  cc = t & 7;
    b  = bb;
    hs = (hi * 8 + r  + 4) & 63;
    ws = (wi * 8 + cc + 4) & 63;
}

// ------------- merged weight convert: 4 segments f32 [K][N] -> bf16 [N][K] --
__global__ __launch_bounds__(256) void k_wt4(const float* __restrict__ qkv_w,
                                             const float* __restrict__ proj_w,
                                             const float* __restrict__ w1,
                                             const float* __restrict__ w2,
                                             unsigned short* __restrict__ d0,
                                             unsigned short* __restrict__ d1,
                                             unsigned short* __restrict__ d2,
                                             unsigned short* __restrict__ d3) {
    int idx = blockIdx.x * 256 + threadIdx.x;
    const float* W; unsigned short* Wt; int K, N, loc;
    if (idx < 442368)       { W = qkv_w;  Wt = d0; K = 384;  N = 1152; loc = idx; }
    else if (idx < 589824)  { W = proj_w; Wt = d1; K = 384;  N = 384;  loc = idx - 442368; }
    else if (idx < 1179648) { W = w1;     Wt = d2; K = 384;  N = 1536; loc = idx - 589824; }
    else                    { W = w2;     Wt = d3; K = 1536; N = 384;  loc = idx - 1179648; }
    int n = loc / K, k = loc - n * K;
    Wt[loc] = f2bf(W[(size_t)k * N + n]);
}

// -------- gather + LayerNorm1, per (b, image-row hs), coalesced ------------
__global__ __launch_bounds__(256) void k_ln1(const float* __restrict__ x,
                                             const float* __restrict__ g,
                                             const float* __restrict__ bt,
                                             unsigned short* __restrict__ ln1) {
    int blk = blockIdx.x;           // b*64 + hs
    int b  = blk >> 6, hs = blk & 63;
    int t  = threadIdx.x;
    int w  = t & 63, cg = t >> 6;   // pixel, channel-group (4)
    const float* row = x + (size_t)b * DIM * 4096 + hs * 64;

    float sum = 0.f, sq = 0.f;
    for (int i = 0; i < 96; i++) {
        int c = i * 4 + cg;
        float v = row[(size_t)c * 4096 + w];
        sum += v; sq += v * v;
    }
    __shared__ float red[2][4][64];
    __shared__ float mean_s[64], rstd_s[64];
    red[0][cg][w] = sum; red[1][cg][w] = sq;
    __syncthreads();
    if (t < 64) {
        float s  = red[0][0][t] + red[0][1][t] + red[0][2][t] + red[0][3][t];
        float q2 = red[1][0][t] + red[1][1][t] + red[1][2][t] + red[1][3][t];
        float mean = s * (1.0f / DIM);
        float var  = q2 * (1.0f / DIM) - mean * mean;
        mean_s[t] = mean;
        rstd_s[t] = rsqrtf(var + 1e-5f);
    }
    __syncthreads();

    int wp = t >> 2, seg = t & 3;
    int hr = (hs + 60) & 63, wr = (wp + 60) & 63;
    int tok = ((b * 8 + (hr >> 3)) * 8 + (wr >> 3)) * 64 + (hr & 7) * 8 + (wr & 7);

    __shared__ __align__(16) unsigned short tile[64][72];
    for (int chunk = 0; chunk < 6; chunk++) {
        float mean = mean_s[w], rstd = rstd_s[w];
        #pragma unroll
        for (int it = 0; it < 16; it++) {
            int cl = it * 4 + cg;
            int c  = chunk * 64 + cl;
            float v = row[(size_t)c * 4096 + w];
            tile[w][cl] = f2bf((v - mean) * rstd * g[c] + bt[c]);
        }
        __syncthreads();
        u16x8 v0 = *(const u16x8*)&tile[wp][seg * 16];
        u16x8 v1 = *(const u16x8*)&tile[wp][seg * 16 + 8];
        unsigned short* op = ln1 + (size_t)tok * DIM + chunk * 64 + seg * 16;
        *(u16x8*)op = v0;
        *(u16x8*)(op + 8) = v1;
        __syncthreads();
    }
}

// ---------------- MFMA GEMM: C[M,N] = A[M,K](bf16) * Bt[N,K]^T(bf16) + bias
// 128x128 tile, 4 waves, 4x4 16x16x32 MFMA, BK=64 single-buffered (2 barriers
// per 32 MFMAs), round-2 direct epilogue (keeps acc in AGPRs: VGPR~80),
// XCD-aware block remap. LDS-staged epilogue deliberately NOT used (rounds
// 4/5: it pushed acc into arch VGPRs, 164 regs, occupancy 31%->11%).
// EPI: 0 bias->bf16; 1 bias+gelu->bf16; 2 bias+residual gather->f32; 3 bias->f32
template <int EPI>
__global__ __launch_bounds__(256) void k_gemm_mfma(
        const unsigned short* __restrict__ A,
        const unsigned short* __restrict__ Bt,
        const float* __restrict__ bias,
        void* __restrict__ Cout,
        const float* __restrict__ xres,
        int N, int K, int GX) {
    __shared__ __align__(16) unsigned short Alds[8 * 128 * 8];  // 16 KB
    __shared__ __align__(16) unsigned short Blds[8 * 128 * 8];  // 16 KB
    int tid  = threadIdx.x;
    int lane = tid & 63;
    int wave = tid >> 6;
    int wm = wave >> 1, wn = wave & 1;
    int quad = lane >> 4, l15 = lane & 15;

    // XCD swizzle: all GX n-blocks of one m-row-block land on one XCD
    int l   = blockIdx.x;
    int xcd = l & 7;
    int r_  = l >> 3;
    int bx  = r_ % GX;
    int by  = (r_ / GX) * 8 + xcd;
    int m0 = by * 128, n0 = bx * 128;

    f32x4 acc[4][4] = {};

    for (int k0 = 0; k0 < K; k0 += 64) {
        // stage 16 KB A + 16 KB B: 32 chunks of 1 KB; 8 chunks per wave
        #pragma unroll
        for (int i = 0; i < 4; i++) {
            int c = wave + i * 4;       // 0..15
            int g = c & 7, j = c >> 3;  // kgroup 0..7, row-half
            const unsigned short* gpA = A + (size_t)(m0 + j * 64 + lane) * K + k0 + g * 8;
            __builtin_amdgcn_global_load_lds(
                (const __attribute__((address_space(1))) void*)gpA,
                (__attribute__((address_space(3))) void*)&Alds[(g * 128 + j * 64) * 8],
                16, 0, 0);
            const unsigned short* gpB = Bt + (size_t)(n0 + j * 64 + lane) * K + k0 + g * 8;
            __builtin_amdgcn_global_load_lds(
                (const __attribute__((address_space(1))) void*)gpB,
                (__attribute__((address_space(3))) void*)&Blds[(g * 128 + j * 64) * 8],
                16, 0, 0);
        }
        __syncthreads();

        #pragma unroll
        for (int kk = 0; kk < 2; kk++) {
            int gq = kk * 4 + quad;     // k-oct index within BK=64
            bf16x8 af[4], bfr[4];
            #pragma unroll
            for (int r = 0; r < 4; r++)
                af[r] = *(const bf16x8*)&Alds[(gq * 128 + wm * 64 + r * 16 + l15) * 8];
            #pragma unroll
            for (int r2 = 0; r2 < 4; r2++)
                bfr[r2] = *(const bf16x8*)&Blds[(gq * 128 + wn * 64 + r2 * 16 + l15) * 8];
            #pragma unroll
            for (int r = 0; r < 4; r++)
                #pragma unroll
                for (int r2 = 0; r2 < 4; r2++)
                    acc[r][r2] = __builtin_amdgcn_mfma_f32_16x16x32_bf16(
                                     af[r], bfr[r2], acc[r][r2], 0, 0, 0);
        }
        __syncthreads();
    }

    // round-2 proven direct epilogue
    #pragma unroll
    for (int r2 = 0; r2 < 4; r2++) {
        int n = n0 + wn * 64 + r2 * 16 + l15;
        float bn = bias[n];
        #pragma unroll
        for (int r = 0; r < 4; r++) {
            #pragma unroll
            for (int reg = 0; reg < 4; reg++) {
                int m = m0 + wm * 64 + r * 16 + quad * 4 + reg;
                float v = acc[r][r2][reg] + bn;
                if (EPI == 0) {
                    ((unsigned short*)Cout)[(size_t)m * N + n] = f2bf(v);
                } else if (EPI == 1) {
                    v = 0.5f * v * (1.0f + erff(v * 0.70710678118654752f));
                    ((unsigned short*)Cout)[(size_t)m * N + n] = f2bf(v);
                } else if (EPI == 2) {
                    int b, hs, ws_;
                    tok2src(m, b, hs, ws_);
                    v += xres[(((size_t)b * DIM + n) * 64 + hs) * 64 + ws_];
                    ((float*)Cout)[(size_t)m * N + n] = v;
                } else {
                    ((float*)Cout)[(size_t)m * N + n] = v;
                }
            }
        }
    }
}

// ---------------- attention per (window, head) — round-2 proven version -----
__global__ __launch_bounds__(64) void k_attn(const unsigned short* __restrict__ qkv,
                                             unsigned short* __restrict__ attn) {
    int win  = blockIdx.x >> 3;
    int head = blockIdx.x & 7;
    int t    = threadIdx.x;
    int tok0 = win * 64;

    __shared__ float Ks[64][52];
    __shared__ float Vs[64][52];

    const unsigned short* rowp = qkv + (size_t)(tok0 + t) * (3 * DIM);
    #pragma unroll
    for (int d = 0; d < HD; d++) {
        Ks[t][d] = bf2f(rowp[DIM + head * HD + d]);
        Vs[t][d] = bf2f(rowp[2 * DIM + head * HD + d]);
    }
    const float scale = 0.14433756729740643f;  // 48^-0.5
    float q[HD];
    #pragma unroll
    for (int d = 0; d < HD; d++) q[d] = bf2f(rowp[head * HD + d]) * scale;
    __syncthreads();

    float s[64];
    float mx = -1e30f;
    #pragma unroll
    for (int m = 0; m < 64; m++) {
        float acc = 0.f;
        #pragma unroll
        for (int d4 = 0; d4 < HD / 4; d4++) {
            float4 kk = *(const float4*)&Ks[m][d4 * 4];
            acc += q[d4 * 4 + 0] * kk.x + q[d4 * 4 + 1] * kk.y
                 + q[d4 * 4 + 2] * kk.z + q[d4 * 4 + 3] * kk.w;
        }
        s[m] = acc;
        mx = fmaxf(mx, acc);
    }
    float denom = 0.f;
    #pragma unroll
    for (int m = 0; m < 64; m++) {
        float e = __expf(s[m] - mx);
        s[m] = e;
        denom += e;
    }
    float inv = 1.0f / denom;
    float out[HD];
    #pragma unroll
    for (int d = 0; d < HD; d++) out[d] = 0.f;
    #pragma unroll
    for (int m = 0; m < 64; m++) {
        float p = s[m] * inv;
        #pragma unroll
        for (int d4 = 0; d4 < HD / 4; d4++) {
            float4 vv = *(const float4*)&Vs[m][d4 * 4];
            out[d4 * 4 + 0] += p * vv.x;
            out[d4 * 4 + 1] += p * vv.y;
            out[d4 * 4 + 2] += p * vv.z;
            out[d4 * 4 + 3] += p * vv.w;
        }
    }
    unsigned short* op = attn + (size_t)(tok0 + t) * DIM + head * HD;
    #pragma unroll
    for (int d = 0; d < HD; d++) op[d] = f2bf(out[d]);
}

// ---------------- LayerNorm2 over y (f32) -> ln2 (bf16) ----------
__global__ __launch_bounds__(64) void k_ln2(const float* __restrict__ y,
                                            const float* __restrict__ g,
                                            const float* __restrict__ bt,
                                            unsigned short* __restrict__ out) {
    int tok = blockIdx.x;
    int t   = threadIdx.x;
    const float* row = y + (size_t)tok * DIM;
    float v[6];
    float sum = 0.f, sq = 0.f;
    #pragma unroll
    for (int i = 0; i < 6; i++) {
        v[i] = row[i * 64 + t];
        sum += v[i]; sq += v[i] * v[i];
    }
    #pragma unroll
    for (int o = 32; o > 0; o >>= 1) {
        sum += __shfl_xor(sum, o, 64);
        sq  += __shfl_xor(sq, o, 64);
    }
    float mean = sum * (1.0f / DIM);
    float var  = sq * (1.0f / DIM) - mean * mean;
    float rstd = rsqrtf(var + 1e-5f);
    unsigned short* orow = out + (size_t)tok * DIM;
    #pragma unroll
    for (int i = 0; i < 6; i++) {
        int c = i * 64 + t;
        orow[c] = f2bf((v[i] - mean) * rstd * g[c] + bt[c]);
    }
}

// ---------------- un-permute + transpose to [B,C,H,W] ------------
__global__ __launch_bounds__(256) void k_out(const float* __restrict__ hbuf,
                                             float* __restrict__ out) {
    int bh = blockIdx.x;
    int b = bh >> 6, h = bh & 63;
    int t = threadIdx.x;
    __shared__ float T[64][193];
    int hh = (h + 60) & 63;
    int hi = hh >> 3, r = hh & 7;
    for (int half = 0; half < 2; half++) {
        int c0 = half * 192;
        for (int idx = t; idx < 64 * 192; idx += 256) {
            int w = idx / 192;
            int c = idx - w * 192;
            int ww = (w + 60) & 63;
            int wi = ww >> 3, cc2 = ww & 7;
            int tok = ((b * 8 + hi) * 8 + wi) * 64 + r * 8 + cc2;
            T[w][c] = hbuf[(size_t)tok * DIM + c0 + c];
        }
        __syncthreads();
        for (int idx = t; idx < 64 * 192; idx += 256) {
            int cc = idx >> 6;
            int w  = idx & 63;
            out[(((size_t)b * DIM + c0 + cc) * 64 + h) * 64 + w] = T[w][cc];
        }
        __syncthreads();
    }
}

extern "C" void kernel_launch(void* const* d_in, const int* in_sizes, int n_in,
                              void* d_out, int out_size, void* d_ws, size_t ws_size,
                              hipStream_t stream) {
    const float* x      = (const float*)d_in[0];
    const float* qkv_w  = (const float*)d_in[1];
    const float* qkv_b  = (const float*)d_in[2];
    const float* proj_w = (const float*)d_in[3];
    const float* proj_b = (const float*)d_in[4];
    const float* ln1_g  = (const float*)d_in[5];
    const float* ln1_b  = (const float*)d_in[6];
    const float* ln2_g  = (const float*)d_in[7];
    const float* ln2_b  = (const float*)d_in[8];
    const float* w1     = (const float*)d_in[9];
    const float* b1     = (const float*)d_in[10];
    const float* w2     = (const float*)d_in[11];
    const float* b2     = (const float*)d_in[12];

    char* ws = (char*)d_ws;
    unsigned short* qkv_wt  = (unsigned short*)(ws + 0);
    unsigned short* proj_wt = (unsigned short*)(ws + 884736);
    unsigned short* w1t     = (unsigned short*)(ws + 1179648);
    unsigned short* w2t     = (unsigned short*)(ws + 2359296);
    unsigned short* ln1     = (unsigned short*)(ws + 4194304);
    unsigned short* qkv     = (unsigned short*)(ws + 29360128);
    unsigned short* attn    = (unsigned short*)(ws + 104857600);
    float*          y       = (float*)(ws + 130023424);
    unsigned short* ln2     = ln1;
    unsigned short* mid     = qkv;      // [32768][1536] bf16
    float*          hbuf    = y;

    k_wt4<<<6912, 256, 0, stream>>>(qkv_w, proj_w, w1, w2, qkv_wt, proj_wt, w1t, w2t);
    k_ln1<<<512, 256, 0, stream>>>(x, ln1_g, ln1_b, ln1);
    k_gemm_mfma<0><<<9 * 256, 256, 0, stream>>>(ln1, qkv_wt, qkv_b, qkv, nullptr, 1152, 384, 9);
    k_attn<<<NWIN * HEADS, 64, 0, stream>>>(qkv, attn);
    k_gemm_mfma<2><<<3 * 256, 256, 0, stream>>>(attn, proj_wt, proj_b, y, x, 384, 384, 3);
    k_ln2<<<NTOK, 64, 0, stream>>>(y, ln2_g, ln2_b, ln2);
    k_gemm_mfma<1><<<12 * 256, 256, 0, stream>>>(ln2, w1t, b1, mid, nullptr, 1536, 384, 12);
    k_gemm_mfma<3><<<3 * 256, 256, 0, stream>>>(mid, w2t, b2, hbuf, nullptr, 384, 1536, 3);
    k_out<<<NWIN, 256, 0, stream>>>(hbuf, (float*)d_out);
}

// Round 7
// 554.854 us; speedup vs baseline: 1.3251x; 1.1533x over previous
//
#include <hip/hip_runtime.h>
#include <hip/hip_bf16.h>
#include <math.h>

#define DIM   384
#define HEADS 8
#define HD    48
#define NTOK  32768   // 8 * 64 * 64
#define NWIN  512     // 8 images * 64 windows

typedef __attribute__((ext_vector_type(8))) short bf16x8;
typedef __attribute__((ext_vector_type(8))) unsigned short u16x8;
typedef __attribute__((ext_vector_type(4))) float f32x4;

__device__ __forceinline__ float bf2f(unsigned short u) {
    unsigned int v = ((unsigned int)u) << 16;
    return __uint_as_float(v);
}
__device__ __forceinline__ unsigned short f2bf(float f) {
    unsigned int x = __float_as_uint(f);
    unsigned int r = (x + 0x7fffu + ((x >> 16) & 1u)) >> 16;  // RNE
    return (unsigned short)r;
}

// token (window order) -> source pixel of x (accounting for roll by -SHIFT)
__device__ __forceinline__ void tok2src(int tok, int& b, int& hs, int& ws) {
    int bb  = tok >> 12;
    int win = (tok >> 6) & 63;
    int t   = tok & 63;
    int hi = win >> 3, wi = win & 7;
    int r  = t >> 3,  cc = t & 7;
    b  = bb;
    hs = (hi * 8 + r  + 4) & 63;
    ws = (wi * 8 + cc + 4) & 63;
}

// ------------- merged weight convert: 4 segments f32 [K][N] -> bf16 [N][K] --
__global__ __launch_bounds__(256) void k_wt4(const float* __restrict__ qkv_w,
                                             const float* __restrict__ proj_w,
                                             const float* __restrict__ w1,
                                             const float* __restrict__ w2,
                                             unsigned short* __restrict__ d0,
                                             unsigned short* __restrict__ d1,
                                             unsigned short* __restrict__ d2,
                                             unsigned short* __restrict__ d3) {
    int idx = blockIdx.x * 256 + threadIdx.x;
    const float* W; unsigned short* Wt; int K, N, loc;
    if (idx < 442368)       { W = qkv_w;  Wt = d0; K = 384;  N = 1152; loc = idx; }
    else if (idx < 589824)  { W = proj_w; Wt = d1; K = 384;  N = 384;  loc = idx - 442368; }
    else if (idx < 1179648) { W = w1;     Wt = d2; K = 384;  N = 1536; loc = idx - 589824; }
    else                    { W = w2;     Wt = d3; K = 1536; N = 384;  loc = idx - 1179648; }
    int n = loc / K, k = loc - n * K;
    Wt[loc] = f2bf(W[(size_t)k * N + n]);
}

// -------- gather + LayerNorm1, per (b, image-row hs), coalesced ------------
__global__ __launch_bounds__(256) void k_ln1(const float* __restrict__ x,
                                             const float* __restrict__ g,
                                             const float* __restrict__ bt,
                                             unsigned short* __restrict__ ln1) {
    int blk = blockIdx.x;           // b*64 + hs
    int b  = blk >> 6, hs = blk & 63;
    int t  = threadIdx.x;
    int w  = t & 63, cg = t >> 6;   // pixel, channel-group (4)
    const float* row = x + (size_t)b * DIM * 4096 + hs * 64;

    float sum = 0.f, sq = 0.f;
    for (int i = 0; i < 96; i++) {
        int c = i * 4 + cg;
        float v = row[(size_t)c * 4096 + w];
        sum += v; sq += v * v;
    }
    __shared__ float red[2][4][64];
    __shared__ float mean_s[64], rstd_s[64];
    red[0][cg][w] = sum; red[1][cg][w] = sq;
    __syncthreads();
    if (t < 64) {
        float s  = red[0][0][t] + red[0][1][t] + red[0][2][t] + red[0][3][t];
        float q2 = red[1][0][t] + red[1][1][t] + red[1][2][t] + red[1][3][t];
        float mean = s * (1.0f / DIM);
        float var  = q2 * (1.0f / DIM) - mean * mean;
        mean_s[t] = mean;
        rstd_s[t] = rsqrtf(var + 1e-5f);
    }
    __syncthreads();

    int wp = t >> 2, seg = t & 3;
    int hr = (hs + 60) & 63, wr = (wp + 60) & 63;
    int tok = ((b * 8 + (hr >> 3)) * 8 + (wr >> 3)) * 64 + (hr & 7) * 8 + (wr & 7);

    __shared__ __align__(16) unsigned short tile[64][72];
    for (int chunk = 0; chunk < 6; chunk++) {
        float mean = mean_s[w], rstd = rstd_s[w];
        #pragma unroll
        for (int it = 0; it < 16; it++) {
            int cl = it * 4 + cg;
            int c  = chunk * 64 + cl;
            float v = row[(size_t)c * 4096 + w];
            tile[w][cl] = f2bf((v - mean) * rstd * g[c] + bt[c]);
        }
        __syncthreads();
        u16x8 v0 = *(const u16x8*)&tile[wp][seg * 16];
        u16x8 v1 = *(const u16x8*)&tile[wp][seg * 16 + 8];
        unsigned short* op = ln1 + (size_t)tok * DIM + chunk * 64 + seg * 16;
        *(u16x8*)op = v0;
        *(u16x8*)(op + 8) = v1;
        __syncthreads();
    }
}

// ---------------- MFMA GEMM: C[M,N] = A[M,K](bf16) * Bt[N,K]^T(bf16) + bias
// 128x128 tile, 4 waves, 4x4 16x16x32 MFMA, BK=64 single-buffered,
// direct epilogue (acc stays in AGPRs), XCD-aware block remap.
// EPI: 0 bias->bf16; 1 bias+gelu->bf16; 2 bias+residual gather->f32;
//      3 bias->f32; 4 bias->bf16 scattered to [qkv][head][tok][48]
template <int EPI>
__global__ __launch_bounds__(256) void k_gemm_mfma(
        const unsigned short* __restrict__ A,
        const unsigned short* __restrict__ Bt,
        const float* __restrict__ bias,
        void* __restrict__ Cout,
        const float* __restrict__ xres,
        int N, int K, int GX) {
    __shared__ __align__(16) unsigned short Alds[8 * 128 * 8];  // 16 KB
    __shared__ __align__(16) unsigned short Blds[8 * 128 * 8];  // 16 KB
    int tid  = threadIdx.x;
    int lane = tid & 63;
    int wave = tid >> 6;
    int wm = wave >> 1, wn = wave & 1;
    int quad = lane >> 4, l15 = lane & 15;

    int l   = blockIdx.x;
    int xcd = l & 7;
    int r_  = l >> 3;
    int bx  = r_ % GX;
    int by  = (r_ / GX) * 8 + xcd;
    int m0 = by * 128, n0 = bx * 128;

    f32x4 acc[4][4] = {};

    for (int k0 = 0; k0 < K; k0 += 64) {
        #pragma unroll
        for (int i = 0; i < 4; i++) {
            int c = wave + i * 4;       // 0..15
            int g = c & 7, j = c >> 3;  // kgroup 0..7, row-half
            const unsigned short* gpA = A + (size_t)(m0 + j * 64 + lane) * K + k0 + g * 8;
            __builtin_amdgcn_global_load_lds(
                (const __attribute__((address_space(1))) void*)gpA,
                (__attribute__((address_space(3))) void*)&Alds[(g * 128 + j * 64) * 8],
                16, 0, 0);
            const unsigned short* gpB = Bt + (size_t)(n0 + j * 64 + lane) * K + k0 + g * 8;
            __builtin_amdgcn_global_load_lds(
                (const __attribute__((address_space(1))) void*)gpB,
                (__attribute__((address_space(3))) void*)&Blds[(g * 128 + j * 64) * 8],
                16, 0, 0);
        }
        __syncthreads();

        #pragma unroll
        for (int kk = 0; kk < 2; kk++) {
            int gq = kk * 4 + quad;     // k-oct index within BK=64
            bf16x8 af[4], bfr[4];
            #pragma unroll
            for (int r = 0; r < 4; r++)
                af[r] = *(const bf16x8*)&Alds[(gq * 128 + wm * 64 + r * 16 + l15) * 8];
            #pragma unroll
            for (int r2 = 0; r2 < 4; r2++)
                bfr[r2] = *(const bf16x8*)&Blds[(gq * 128 + wn * 64 + r2 * 16 + l15) * 8];
            #pragma unroll
            for (int r = 0; r < 4; r++)
                #pragma unroll
                for (int r2 = 0; r2 < 4; r2++)
                    acc[r][r2] = __builtin_amdgcn_mfma_f32_16x16x32_bf16(
                                     af[r], bfr[r2], acc[r][r2], 0, 0, 0);
        }
        __syncthreads();
    }

    #pragma unroll
    for (int r2 = 0; r2 < 4; r2++) {
        int n = n0 + wn * 64 + r2 * 16 + l15;
        float bn = bias[n];
        #pragma unroll
        for (int r = 0; r < 4; r++) {
            #pragma unroll
            for (int reg = 0; reg < 4; reg++) {
                int m = m0 + wm * 64 + r * 16 + quad * 4 + reg;
                float v = acc[r][r2][reg] + bn;
                if (EPI == 0) {
                    ((unsigned short*)Cout)[(size_t)m * N + n] = f2bf(v);
                } else if (EPI == 1) {
                    v = 0.5f * v * (1.0f + erff(v * 0.70710678118654752f));
                    ((unsigned short*)Cout)[(size_t)m * N + n] = f2bf(v);
                } else if (EPI == 2) {
                    int b, hs, ws_;
                    tok2src(m, b, hs, ws_);
                    v += xres[(((size_t)b * DIM + n) * 64 + hs) * 64 + ws_];
                    ((float*)Cout)[(size_t)m * N + n] = v;
                } else if (EPI == 3) {
                    ((float*)Cout)[(size_t)m * N + n] = v;
                } else {
                    // head-major qkv scatter: [qkv(3)][head(8)][tok][48]
                    int qi  = n / 384;
                    int rem = n - qi * 384;
                    int hh  = rem / 48;
                    int d   = rem - hh * 48;
                    ((unsigned short*)Cout)[((size_t)(qi * 8 + hh) * NTOK + m) * 48 + d] = f2bf(v);
                }
            }
        }
    }
}

// ---------------- MFMA attention: 1 block = 1 window, 4 waves x 2 heads -----
// qkvh layout: [qkv(3)][head(8)][tok(32768)][48] bf16.
// Frag layouts identical to the proven GEMM: A: m=l15,k=quad*8+j;
// B: n=l15,k=quad*8+j; C/D: col=l15,row=quad*4+reg.
__global__ __launch_bounds__(256) void k_attn_mfma(
        const unsigned short* __restrict__ qkvh,
        unsigned short* __restrict__ attn) {
    // per-wave LDS: VT [48][72] (3456 u16) + P [64][72] (4608 u16) = 8064 u16
    __shared__ __align__(16) unsigned short lds[4][8064];   // 64512 B total
    int tid  = threadIdx.x;
    int lane = tid & 63;
    int wave = tid >> 6;
    int quad = lane >> 4, l15 = lane & 15;
    int win  = blockIdx.x;
    int tok0 = win * 64;
    unsigned short* VT = &lds[wave][0];
    unsigned short* P  = &lds[wave][3456];
    const float scale = 0.14433756729740643f;  // 48^-0.5

    for (int hi = 0; hi < 2; hi++) {
        int h = wave + hi * 4;
        const unsigned short* qb = qkvh + ((size_t)(0 * 8 + h) * NTOK + tok0) * 48;
        const unsigned short* kb = qkvh + ((size_t)(1 * 8 + h) * NTOK + tok0) * 48;
        const unsigned short* vb = qkvh + ((size_t)(2 * 8 + h) * NTOK + tok0) * 48;

        // stage V^T into LDS: lane = token, write column `lane`
        #pragma unroll
        for (int i = 0; i < 6; i++) {
            u16x8 v = *(const u16x8*)&vb[lane * 48 + i * 8];
            #pragma unroll
            for (int j = 0; j < 8; j++)
                VT[(i * 8 + j) * 72 + lane] = v[j];
        }

        // K fragments (B-operand of QK^T): kf[ni][chunk]
        bf16x8 kf[4][2];
        #pragma unroll
        for (int ni = 0; ni < 4; ni++) {
            kf[ni][0] = *(const bf16x8*)&kb[(ni * 16 + l15) * 48 + quad * 8];
            bf16x8 z = {};
            if (quad < 2)
                z = *(const bf16x8*)&kb[(ni * 16 + l15) * 48 + 32 + quad * 8];
            kf[ni][1] = z;   // d in [48,64) zero-masked
        }

        // S = Q K^T   (64x64, K=48 padded to 64 with zeros)
        f32x4 sacc[4][4] = {};
        #pragma unroll
        for (int mi = 0; mi < 4; mi++) {
            bf16x8 qf0 = *(const bf16x8*)&qb[(mi * 16 + l15) * 48 + quad * 8];
            bf16x8 qf1 = {};
            if (quad < 2)
                qf1 = *(const bf16x8*)&qb[(mi * 16 + l15) * 48 + 32 + quad * 8];
            #pragma unroll
            for (int ni = 0; ni < 4; ni++) {
                sacc[mi][ni] = __builtin_amdgcn_mfma_f32_16x16x32_bf16(qf0, kf[ni][0], sacc[mi][ni], 0, 0, 0);
                sacc[mi][ni] = __builtin_amdgcn_mfma_f32_16x16x32_bf16(qf1, kf[ni][1], sacc[mi][ni], 0, 0, 0);
            }
        }

        // softmax over rows (C-layout: row=quad*4+reg, col=ni*16+l15), P -> LDS
        #pragma unroll
        for (int mi = 0; mi < 4; mi++) {
            #pragma unroll
            for (int reg = 0; reg < 4; reg++) {
                float s0 = sacc[mi][0][reg] * scale;
                float s1 = sacc[mi][1][reg] * scale;
                float s2 = sacc[mi][2][reg] * scale;
                float s3 = sacc[mi][3][reg] * scale;
                float mx = fmaxf(fmaxf(s0, s1), fmaxf(s2, s3));
                #pragma unroll
                for (int off = 1; off < 16; off <<= 1)
                    mx = fmaxf(mx, __shfl_xor(mx, off));
                float e0 = __expf(s0 - mx);
                float e1 = __expf(s1 - mx);
                float e2 = __expf(s2 - mx);
                float e3 = __expf(s3 - mx);
                float sm = e0 + e1 + e2 + e3;
                #pragma unroll
                for (int off = 1; off < 16; off <<= 1)
                    sm += __shfl_xor(sm, off);
                float inv = 1.0f / sm;
                int row = mi * 16 + quad * 4 + reg;
                P[row * 72 +  0 + l15] = f2bf(e0 * inv);
                P[row * 72 + 16 + l15] = f2bf(e1 * inv);
                P[row * 72 + 32 + l15] = f2bf(e2 * inv);
                P[row * 72 + 48 + l15] = f2bf(e3 * inv);
            }
        }

        // O = P V   (64x48, K=64); V^T fragments from LDS
        bf16x8 vf[3][2];
        #pragma unroll
        for (int ni = 0; ni < 3; ni++)
            #pragma unroll
            for (int kt = 0; kt < 2; kt++)
                vf[ni][kt] = *(const bf16x8*)&VT[(ni * 16 + l15) * 72 + kt * 32 + quad * 8];

        #pragma unroll
        for (int mi = 0; mi < 4; mi++) {
            bf16x8 pf0 = *(const bf16x8*)&P[(mi * 16 + l15) * 72 + quad * 8];
            bf16x8 pf1 = *(const bf16x8*)&P[(mi * 16 + l15) * 72 + 32 + quad * 8];
            f32x4 o[3] = {};
            #pragma unroll
            for (int ni = 0; ni < 3; ni++) {
                o[ni] = __builtin_amdgcn_mfma_f32_16x16x32_bf16(pf0, vf[ni][0], o[ni], 0, 0, 0);
                o[ni] = __builtin_amdgcn_mfma_f32_16x16x32_bf16(pf1, vf[ni][1], o[ni], 0, 0, 0);
            }
            #pragma unroll
            for (int ni = 0; ni < 3; ni++)
                #pragma unroll
                for (int reg = 0; reg < 4; reg++) {
                    int tok = tok0 + mi * 16 + quad * 4 + reg;
                    attn[(size_t)tok * DIM + h * HD + ni * 16 + l15] = f2bf(o[ni][reg]);
                }
        }
    }
}

// ---------------- LayerNorm2 over y (f32) -> ln2 (bf16) ----------
__global__ __launch_bounds__(64) void k_ln2(const float* __restrict__ y,
                                            const float* __restrict__ g,
                                            const float* __restrict__ bt,
                                            unsigned short* __restrict__ out) {
    int tok = blockIdx.x;
    int t   = threadIdx.x;
    const float* row = y + (size_t)tok * DIM;
    float v[6];
    float sum = 0.f, sq = 0.f;
    #pragma unroll
    for (int i = 0; i < 6; i++) {
        v[i] = row[i * 64 + t];
        sum += v[i]; sq += v[i] * v[i];
    }
    #pragma unroll
    for (int o = 32; o > 0; o >>= 1) {
        sum += __shfl_xor(sum, o, 64);
        sq  += __shfl_xor(sq, o, 64);
    }
    float mean = sum * (1.0f / DIM);
    float var  = sq * (1.0f / DIM) - mean * mean;
    float rstd = rsqrtf(var + 1e-5f);
    unsigned short* orow = out + (size_t)tok * DIM;
    #pragma unroll
    for (int i = 0; i < 6; i++) {
        int c = i * 64 + t;
        orow[c] = f2bf((v[i] - mean) * rstd * g[c] + bt[c]);
    }
}

// ---------------- un-permute + transpose to [B,C,H,W] ------------
__global__ __launch_bounds__(256) void k_out(const float* __restrict__ hbuf,
                                             float* __restrict__ out) {
    int bh = blockIdx.x;
    int b = bh >> 6, h = bh & 63;
    int t = threadIdx.x;
    __shared__ float T[64][193];
    int hh = (h + 60) & 63;
    int hi = hh >> 3, r = hh & 7;
    for (int half = 0; half < 2; half++) {
        int c0 = half * 192;
        for (int idx = t; idx < 64 * 192; idx += 256) {
            int w = idx / 192;
            int c = idx - w * 192;
            int ww = (w + 60) & 63;
            int wi = ww >> 3, cc2 = ww & 7;
            int tok = ((b * 8 + hi) * 8 + wi) * 64 + r * 8 + cc2;
            T[w][c] = hbuf[(size_t)tok * DIM + c0 + c];
        }
        __syncthreads();
        for (int idx = t; idx < 64 * 192; idx += 256) {
            int cc = idx >> 6;
            int w  = idx & 63;
            out[(((size_t)b * DIM + c0 + cc) * 64 + h) * 64 + w] = T[w][cc];
        }
        __syncthreads();
    }
}

extern "C" void kernel_launch(void* const* d_in, const int* in_sizes, int n_in,
                              void* d_out, int out_size, void* d_ws, size_t ws_size,
                              hipStream_t stream) {
    const float* x      = (const float*)d_in[0];
    const float* qkv_w  = (const float*)d_in[1];
    const float* qkv_b  = (const float*)d_in[2];
    const float* proj_w = (const float*)d_in[3];
    const float* proj_b = (const float*)d_in[4];
    const float* ln1_g  = (const float*)d_in[5];
    const float* ln1_b  = (const float*)d_in[6];
    const float* ln2_g  = (const float*)d_in[7];
    const float* ln2_b  = (const float*)d_in[8];
    const float* w1     = (const float*)d_in[9];
    const float* b1     = (const float*)d_in[10];
    const float* w2     = (const float*)d_in[11];
    const float* b2     = (const float*)d_in[12];

    char* ws = (char*)d_ws;
    unsigned short* qkv_wt  = (unsigned short*)(ws + 0);
    unsigned short* proj_wt = (unsigned short*)(ws + 884736);
    unsigned short* w1t     = (unsigned short*)(ws + 1179648);
    unsigned short* w2t     = (unsigned short*)(ws + 2359296);
    unsigned short* ln1     = (unsigned short*)(ws + 4194304);
    unsigned short* qkv     = (unsigned short*)(ws + 29360128);   // [3][8][32768][48]
    unsigned short* attn    = (unsigned short*)(ws + 104857600);
    float*          y       = (float*)(ws + 130023424);
    unsigned short* ln2     = ln1;
    unsigned short* mid     = qkv;      // [32768][1536] bf16
    float*          hbuf    = y;

    k_wt4<<<6912, 256, 0, stream>>>(qkv_w, proj_w, w1, w2, qkv_wt, proj_wt, w1t, w2t);
    k_ln1<<<512, 256, 0, stream>>>(x, ln1_g, ln1_b, ln1);
    k_gemm_mfma<4><<<9 * 256, 256, 0, stream>>>(ln1, qkv_wt, qkv_b, qkv, nullptr, 1152, 384, 9);
    k_attn_mfma<<<NWIN, 256, 0, stream>>>(qkv, attn);
    k_gemm_mfma<2><<<3 * 256, 256, 0, stream>>>(attn, proj_wt, proj_b, y, x, 384, 384, 3);
    k_ln2<<<NTOK, 64, 0, stream>>>(y, ln2_g, ln2_b, ln2);
    k_gemm_mfma<1><<<12 * 256, 256, 0, stream>>>(ln2, w1t, b1, mid, nullptr, 1536, 384, 12);
    k_gemm_mfma<3><<<3 * 256, 256, 0, stream>>>(mid, w2t, b2, hbuf, nullptr, 384, 1536, 3);
    k_out<<<NWIN, 256, 0, stream>>>(hbuf, (float*)d_out);
}